// Round 9
// baseline (425.559 us; speedup 1.0000x reference)
//
#include <hip/hip_runtime.h>
#include <math.h>

#define NND 50000
#define DEG 16

typedef __attribute__((ext_vector_type(8))) short short8v;
typedef __attribute__((ext_vector_type(4))) float float4v;

// ---- workspace layout (bytes) ----
#define OFF_HPRE 0ULL            // N x 64 f32
#define OFF_PROJ 12800000ULL     // 4 x N x 64 f32
#define OFF_XB   64000000ULL     // N x 128 bf16
#define OFF_IDX  102400000ULL    // 5*N int
#define OFF_BQF  103600384ULL    // 4y x 8c x 8ct x 64 x 8 bf16 = 256 KB
#define OFF_WOF  103862528ULL    // 4c x 8ct x 64 x 8 bf16 = 32 KB
#define WS_NEED  103895296ULL

#define LOG2E 1.44269504088896f

__device__ __forceinline__ float fast_sig(float x){
    return __builtin_amdgcn_rcpf(1.f + __builtin_amdgcn_exp2f(-LOG2E*x));
}
__device__ __forceinline__ float fast_tanh(float x){
    return fmaf(-2.f, __builtin_amdgcn_rcpf(1.f + __builtin_amdgcn_exp2f((2.f*LOG2E)*x)), 1.f);
}
__device__ __forceinline__ unsigned short f2bf(float f){
    unsigned int u = __float_as_uint(f);
    u += 0x7FFFu + ((u >> 16) & 1u);
    return (unsigned short)(u >> 16);
}
__device__ __forceinline__ float bf2f(unsigned short h){
    return __uint_as_float(((unsigned int)h) << 16);
}

// ---------------- fused setup: iota + pack_x + pack_bqf + pack_wof ----------------
__global__ __launch_bounds__(256) void k_setup(const float* __restrict__ na,
    const float* __restrict__ Wx, const float* __restrict__ Wh,
    const float* __restrict__ Wo, unsigned short* __restrict__ Xb,
    unsigned short* __restrict__ BqF, unsigned short* __restrict__ WoF,
    int* __restrict__ idx0)
{
    const int b = blockIdx.x, tid = threadIdx.x;
    {
        int i = b*256 + tid;
        if (i < NND*32){
            float4 v = *(const float4*)(na + (size_t)i*4);
            unsigned long long pk = (unsigned long long)f2bf(v.x)
                | ((unsigned long long)f2bf(v.y) << 16)
                | ((unsigned long long)f2bf(v.z) << 32)
                | ((unsigned long long)f2bf(v.w) << 48);
            *(unsigned long long*)(Xb + (size_t)i*4) = pk;
        }
    }
    if (b < 512){
        int i = b*256 + tid;  // 131072
        int jj = i & 7, lane = (i>>3)&63, ct = (i>>9)&7, c = (i>>12)&7, y = i>>15;
        int g = ct>>1, jh = ct&1, mm = lane&15, quad = lane>>4;
        int jg = (y<<5) + (jh<<4) + mm;
        int k = (c<<5) + (quad<<3) + jj;
        float v = 0.f;
        if (k < 128){
            if (g < 3) v = Wh[k*384 + g*128 + jg];
        } else {
            int kk = k - 128;
            if (g == 0)      v = Wx[kk*384 + jg];
            else if (g == 1) v = Wx[kk*384 + 128 + jg];
            else if (g == 3) v = Wx[kk*384 + 256 + jg];
        }
        BqF[i] = f2bf(v);
    } else if (b < 576){
        int i = (b-512)*256 + tid;  // 16384
        int jj = i & 7, lane = (i>>3)&63, ct = (i>>9)&7, c = i>>12;
        int n = (ct<<4) + (lane&15);
        int k = (c<<5) + ((lane>>4)<<3) + jj;
        WoF[i] = f2bf(Wo[k*128 + n]);
    } else if (b < 772){
        int i = (b-576)*256 + tid;
        if (i < NND) idx0[i] = i;
    }
}

// ---------------- walk phase (fp32, argmax determinism) ----------------
// v8: 256r x 128c blocks (y-pairs share A staging). Accumulation order
// (k0 asc, k asc, fmaf chain) fixed -> bit-exact.
__global__ __launch_bounds__(256,2) void k_projall(const float* __restrict__ A,
    const float* __restrict__ W1, const float* __restrict__ bias1,
    float* __restrict__ hpre, float* __restrict__ proj)
{
    __shared__ float Alt[32][320];     // [k][sr], sr = row + (row>>4)*4 (40KB)
    __shared__ float Bl[32][140];      // [k][scol], scol = col + (col>>5)*4 (17.5KB)
    const int tid = threadIdx.x;
    const int row0 = blockIdx.x << 8;  // 256 rows/block
    const int z = blockIdx.y;          // 0:{y0,y1} 1:{y2,y3} 2:{y4}
    const int row_t = tid >> 4, col_t = tid & 15;
    const int sr_st = tid + ((tid>>4)<<2);   // staging swizzled row for thread's row
    int gr_st = row0 + tid; if (gr_st >= NND) gr_st = NND-1;
    const float* ap = A + (size_t)gr_st*128;

    if (z < 2){
        float4 acc[16][2];
#pragma unroll
        for (int j=0;j<16;j++){ acc[j][0]=make_float4(0,0,0,0); acc[j][1]=make_float4(0,0,0,0); }
        const int cb = col_t << 3;
        const int scb = cb + ((cb>>5)<<2);
        for (int k0 = 0; k0 < 128; k0 += 32){
#pragma unroll
            for (int u=0;u<8;u++){
                float4 v = *(const float4*)(ap + k0 + (u<<2));
                Alt[(u<<2)+0][sr_st] = v.x; Alt[(u<<2)+1][sr_st] = v.y;
                Alt[(u<<2)+2][sr_st] = v.z; Alt[(u<<2)+3][sr_st] = v.w;
            }
#pragma unroll
            for (int i=0;i<4;i++){
                int p = (i<<8) + tid;
                int ch = p >> 9, rem = p & 511;
                int bk = rem >> 4, bc = (rem & 15) << 2;
                int col = (ch<<6) + bc;
                int sc = col + ((col>>5)<<2);
                *(float4*)(&Bl[bk][sc]) =
                    *(const float4*)(W1 + (size_t)(((z*2+ch)<<7) + k0 + bk)*64 + bc);
            }
            __syncthreads();
#pragma unroll 2
            for (int k=0;k<32;k++){
                const float* ar = &Alt[k][row_t*20];
                float4 a0 = *(const float4*)(ar);
                float4 a1 = *(const float4*)(ar+4);
                float4 a2 = *(const float4*)(ar+8);
                float4 a3 = *(const float4*)(ar+12);
                float4 b0 = *(const float4*)(&Bl[k][scb]);
                float4 b1 = *(const float4*)(&Bl[k][scb+4]);
                float av[16] = {a0.x,a0.y,a0.z,a0.w, a1.x,a1.y,a1.z,a1.w,
                                a2.x,a2.y,a2.z,a2.w, a3.x,a3.y,a3.z,a3.w};
#pragma unroll
                for (int j=0;j<16;j++){
                    acc[j][0].x = fmaf(av[j], b0.x, acc[j][0].x);
                    acc[j][0].y = fmaf(av[j], b0.y, acc[j][0].y);
                    acc[j][0].z = fmaf(av[j], b0.z, acc[j][0].z);
                    acc[j][0].w = fmaf(av[j], b0.w, acc[j][0].w);
                    acc[j][1].x = fmaf(av[j], b1.x, acc[j][1].x);
                    acc[j][1].y = fmaf(av[j], b1.y, acc[j][1].y);
                    acc[j][1].z = fmaf(av[j], b1.z, acc[j][1].z);
                    acc[j][1].w = fmaf(av[j], b1.w, acc[j][1].w);
                }
            }
            __syncthreads();
        }
        float* dlo = (z==0) ? hpre : (proj + (size_t)(2*z-1)*NND*64);
        float* dhi = proj + (size_t)(2*z)*NND*64;
        float* dstp = (col_t < 8) ? dlo : dhi;
        const int ccol = (col_t & 7) << 3;
        float4 bb0 = make_float4(0,0,0,0), bb1 = make_float4(0,0,0,0);
        if (z == 0 && col_t < 8){
            bb0 = *(const float4*)(bias1 + ccol);
            bb1 = *(const float4*)(bias1 + ccol + 4);
        }
#pragma unroll
        for (int j=0;j<16;j++){
            int gr = row0 + (row_t<<4) + j;
            if (gr < NND){
                float4 o0 = make_float4(acc[j][0].x+bb0.x, acc[j][0].y+bb0.y,
                                        acc[j][0].z+bb0.z, acc[j][0].w+bb0.w);
                float4 o1 = make_float4(acc[j][1].x+bb1.x, acc[j][1].y+bb1.y,
                                        acc[j][1].z+bb1.z, acc[j][1].w+bb1.w);
                *(float4*)(dstp + ((size_t)gr<<6) + ccol)     = o0;
                *(float4*)(dstp + ((size_t)gr<<6) + ccol + 4) = o1;
            }
        }
    } else {
        float4 acc[16];
#pragma unroll
        for (int j=0;j<16;j++) acc[j] = make_float4(0,0,0,0);
        const int cb = col_t << 2;
        const int scb = cb + ((cb>>5)<<2);
        for (int k0 = 0; k0 < 128; k0 += 32){
#pragma unroll
            for (int u=0;u<8;u++){
                float4 v = *(const float4*)(ap + k0 + (u<<2));
                Alt[(u<<2)+0][sr_st] = v.x; Alt[(u<<2)+1][sr_st] = v.y;
                Alt[(u<<2)+2][sr_st] = v.z; Alt[(u<<2)+3][sr_st] = v.w;
            }
#pragma unroll
            for (int i=0;i<2;i++){
                int p = (i<<8) + tid;     // 512 float4
                int bk = p >> 4, bc = (p & 15) << 2;
                int sc = bc + ((bc>>5)<<2);
                *(float4*)(&Bl[bk][sc]) =
                    *(const float4*)(W1 + (size_t)((4<<7) + k0 + bk)*64 + bc);
            }
            __syncthreads();
#pragma unroll 2
            for (int k=0;k<32;k++){
                const float* ar = &Alt[k][row_t*20];
                float4 a0 = *(const float4*)(ar);
                float4 a1 = *(const float4*)(ar+4);
                float4 a2 = *(const float4*)(ar+8);
                float4 a3 = *(const float4*)(ar+12);
                float4 b0 = *(const float4*)(&Bl[k][scb]);
                float av[16] = {a0.x,a0.y,a0.z,a0.w, a1.x,a1.y,a1.z,a1.w,
                                a2.x,a2.y,a2.z,a2.w, a3.x,a3.y,a3.z,a3.w};
#pragma unroll
                for (int j=0;j<16;j++){
                    acc[j].x = fmaf(av[j], b0.x, acc[j].x);
                    acc[j].y = fmaf(av[j], b0.y, acc[j].y);
                    acc[j].z = fmaf(av[j], b0.z, acc[j].z);
                    acc[j].w = fmaf(av[j], b0.w, acc[j].w);
                }
            }
            __syncthreads();
        }
        float* dstp = proj + (size_t)3*NND*64;
#pragma unroll
        for (int j=0;j<16;j++){
            int gr = row0 + (row_t<<4) + j;
            if (gr < NND)
                *(float4*)(dstp + ((size_t)gr<<6) + cb) = acc[j];
        }
    }
}

// ---------------- walk4 v3 (round-8, kept): reduce-scatter logits ----------------
// HBM/L2-miss-path bound: dur == FETCH/3.5TB/s; 332MB is structural
// (proj[t]=12.8MB > 4MB XCD L2, random gathers re-pulled per XCD per step).
__global__ __launch_bounds__(256) void k_walk4(
    const float* __restrict__ hpre0, const float* __restrict__ proj,
    const int* __restrict__ dst, const float* __restrict__ W2,
    const float* __restrict__ b2, const float* __restrict__ noise,
    int* __restrict__ idxb)
{
    const int tid = threadIdx.x;
    const int sg = tid >> 4, l = tid & 15;
    const int gi = (blockIdx.x << 4) + sg;
    float4 hp = *(const float4*)(hpre0 + ((size_t)gi<<6) + (l<<2));
    float4 w2 = *(const float4*)(W2 + (l<<2));
    const float b2s = b2[0];
    int curv = gi;
#pragma unroll 1
    for (int t=0; t<4; t++){
        const float* pj = proj + (size_t)t*NND*64;
        const int base = curv*DEG;
        const int nbr = dst[base + l];              // per-lane id (for sel shfl)
        int4 nb0 = *(const int4*)(dst + base);      // uniform in subgroup: L1 broadcast
        int4 nb1 = *(const int4*)(dst + base + 4);
        int4 nb2 = *(const int4*)(dst + base + 8);
        int4 nb3 = *(const int4*)(dst + base + 12);
        int nds[16] = {nb0.x,nb0.y,nb0.z,nb0.w, nb1.x,nb1.y,nb1.z,nb1.w,
                       nb2.x,nb2.y,nb2.z,nb2.w, nb3.x,nb3.y,nb3.z,nb3.w};
        float4 val[16];
#pragma unroll
        for (int d=0; d<16; d++)
            val[d] = *(const float4*)(pj + ((size_t)nds[d]<<6) + (l<<2));
        float q[16];
#pragma unroll
        for (int d=0; d<16; d++){
            float4 v = val[d];
            float qq =  fmaxf(hp.x+v.x,0.f)*w2.x;
            qq = fmaf(fmaxf(hp.y+v.y,0.f), w2.y, qq);
            qq = fmaf(fmaxf(hp.z+v.z,0.f), w2.z, qq);
            qq = fmaf(fmaxf(hp.w+v.w,0.f), w2.w, qq);
            q[d] = qq;
        }
        // reduce-scatter butterfly: 15 shuffles, logit l ends in lane l. BIT-EXACT.
        float r1[8];
#pragma unroll
        for (int i=0;i<8;i++){
            float a = q[2*i], b = q[2*i+1];
            float send = (l&1) ? a : b;
            float keep = (l&1) ? b : a;
            r1[i] = keep + __shfl_xor(send, 1, 16);
        }
        float r2[4];
#pragma unroll
        for (int i=0;i<4;i++){
            float a = r1[2*i], b = r1[2*i+1];
            float send = (l&2) ? a : b;
            float keep = (l&2) ? b : a;
            r2[i] = keep + __shfl_xor(send, 2, 16);
        }
        float r3[2];
#pragma unroll
        for (int i=0;i<2;i++){
            float a = r2[2*i], b = r2[2*i+1];
            float send = (l&4) ? a : b;
            float keep = (l&4) ? b : a;
            r3[i] = keep + __shfl_xor(send, 4, 16);
        }
        float lp;
        {
            float a = r3[0], b = r3[1];
            float send = (l&8) ? a : b;
            float keep = (l&8) ? b : a;
            lp = keep + __shfl_xor(send, 8, 16) + b2s;
        }
        float mx = lp;
#pragma unroll
        for (int off=8; off; off>>=1) mx = fmaxf(mx, __shfl_xor(mx, off, 16));
        float s = expf(lp - mx);
#pragma unroll
        for (int off=8; off; off>>=1) s += __shfl_xor(s, off, 16);
        float p = expf(lp - mx - logf(s)) + noise[(size_t)t*NND*DEG + ((size_t)gi<<4) + l];
        float bv = p; int bi = l;
#pragma unroll
        for (int off=8; off; off>>=1){
            float ov = __shfl_xor(bv, off, 16);
            int   oi = __shfl_xor(bi, off, 16);
            if (ov > bv || (ov == bv && oi < bi)){ bv = ov; bi = oi; }
        }
        int sel = __shfl(nbr, bi, 16);
        if (l == 0) idxb[(size_t)(t+1)*NND + gi] = sel;
        float4 u = *(const float4*)(pj + ((size_t)sel<<6) + (l<<2));
        hp.x += u.x; hp.y += u.y; hp.z += u.z; hp.w += u.w;
        curv = sel;
    }
}

// ---------------- fully fused GRU (5 steps) + output GEMM ----------------
// v8: REGISTER-DIET two-pass. Evidence: VGPR pool = 2048/CU; old wave used
// 116 VGPR + 128 AGPR (acc[32]) = 244 -> hard 2 waves/SIMD cap (r1's (256,3)
// forced ~170 budget -> catastrophic spill). Splitting each step into two
// jh-passes (acc[16] = 64 AGPR each, A/X frags re-read per pass) cuts the
// wave to ~160 combined -> (256,3) feasible. LDS cut to 48KB (single A_l,
// 2 barriers/step) so 3 blocks/CU fit. Per-acc accumulation order (c asc,
// h-part then x-part) unchanged -> bit-exact. Zero-frag skip kept.
// FAILURE SIGNATURE (revert if seen): VGPR at cap + FETCH/WRITE explosion.
__global__ __launch_bounds__(256,3) void k_gru5(
    const unsigned short* __restrict__ Xb,
    const unsigned short* __restrict__ BqF,
    const unsigned short* __restrict__ WoF,
    const float* __restrict__ bx, const float* __restrict__ bh,
    const float* __restrict__ bo, const int* __restrict__ idxb,
    float* __restrict__ out)
{
    __shared__ unsigned short A_l[8192];     // h frags, single buffer (16KB)
    __shared__ unsigned short X_l[16384];    // x frags, 2 buffers of 8192 (32KB)
    const int tid = threadIdx.x;
    const int w = tid >> 6, lane = tid & 63;
    const int m = lane & 15, quad = lane >> 4;
    const int r = tid & 63, q = tid >> 6;
    const int rt_s = r >> 4, m_s = r & 15;
    float brr[2], bzz[2], bxn[2], bhn[2];
#pragma unroll
    for (int jh=0; jh<2; jh++){
        int j = (w<<5) + (jh<<4) + m;
        brr[jh] = bx[j] + bh[j];
        bzz[jh] = bx[128+j] + bh[128+j];
        bxn[jh] = bx[256+j];
        bhn[jh] = bh[256+j];
    }

#pragma unroll 1
    for (int tb = blockIdx.x; tb < 782; tb += 768){
        const int row0 = tb << 6;
        int gr = row0 + r; if (gr >= NND) gr = NND-1;
        unsigned short holdv[2][4][4];
        short8v xv[4];
        {
            const int xr = idxb[gr];
            const unsigned short* xrow = Xb + (size_t)xr*128 + (q<<5);
#pragma unroll
            for (int u=0;u<4;u++) xv[u] = *(const short8v*)(xrow + (u<<3));
#pragma unroll
            for (int u=0;u<4;u++)
                *(short8v*)(X_l + (((rt_s<<2)+q)*64 + (u<<4) + m_s)*8) = xv[u];
            const int xr1 = idxb[NND + gr];
            const unsigned short* xrow1 = Xb + (size_t)xr1*128 + (q<<5);
#pragma unroll
            for (int u=0;u<4;u++) xv[u] = *(const short8v*)(xrow1 + (u<<3));
        }
        __syncthreads();   // X_l[0] ready (also guards prev tile's A_l reads)

#pragma unroll 1
        for (int s=0; s<5; s++){
            const unsigned short* Xcur = X_l + ((s&1)<<13);
            // early x-staging: Xnxt parity last read in step s-1 (barrier passed)
            if (s < 4){
                unsigned short* Xnxt = X_l + (((s+1)&1)<<13);
#pragma unroll
                for (int u=0;u<4;u++)
                    *(short8v*)(Xnxt + (((rt_s<<2)+q)*64 + (u<<4) + m_s)*8) = xv[u];
                if (s < 3){
                    const int xr = idxb[(size_t)(s+2)*NND + gr];
                    const unsigned short* xrow = Xb + (size_t)xr*128 + (q<<5);
#pragma unroll
                    for (int u=0;u<4;u++) xv[u] = *(const short8v*)(xrow + (u<<3));
                }
            }
            // two passes over jh: acc[16] each (64 regs), gates g: 0=r,1=z,2=hn,3=xn
#pragma unroll 1
            for (int jh=0; jh<2; jh++){
                float4v zero = {0.f,0.f,0.f,0.f};
                float4v acc[16];   // [g4][rt4]
#pragma unroll
                for (int i=0;i<16;i++) acc[i] = zero;
                // h-part: c=0..3 from A_l; xn (g=3) zero over h rows -> skip
                if (s > 0){
#pragma unroll 1
                    for (int c=0;c<4;c++){
                        short8v afr[4];
#pragma unroll
                        for (int rt=0;rt<4;rt++)
                            afr[rt] = *(const short8v*)(A_l + (((rt<<2) + c)*64 + lane)*8);
                        const unsigned short* bp = BqF + ((((size_t)w*8 + c)*8)*64 + lane)*8;
#pragma unroll
                        for (int g=0;g<3;g++){
                            const int ct = (g<<1) + jh;
                            short8v bf = *(const short8v*)(bp + (ct<<9));
#pragma unroll
                            for (int rt=0;rt<4;rt++)
                                acc[(g<<2)+rt] = __builtin_amdgcn_mfma_f32_16x16x32_bf16(afr[rt], bf, acc[(g<<2)+rt], 0,0,0);
                        }
                    }
                }
                // x-part: c=4..7 from Xcur; hn (g=2) zero over x rows -> skip
#pragma unroll 1
                for (int c=4;c<8;c++){
                    short8v afr[4];
#pragma unroll
                    for (int rt=0;rt<4;rt++)
                        afr[rt] = *(const short8v*)(Xcur + (((rt<<2) + (c&3))*64 + lane)*8);
                    const unsigned short* bp = BqF + ((((size_t)w*8 + c)*8)*64 + lane)*8;
#pragma unroll
                    for (int gi2=0;gi2<3;gi2++){
                        const int g = (gi2 < 2) ? gi2 : 3;
                        const int ct = (g<<1) + jh;
                        short8v bf = *(const short8v*)(bp + (ct<<9));
#pragma unroll
                        for (int rt=0;rt<4;rt++)
                            acc[(g<<2)+rt] = __builtin_amdgcn_mfma_f32_16x16x32_bf16(afr[rt], bf, acc[(g<<2)+rt], 0,0,0);
                    }
                }
                // epilogue for this jh
#pragma unroll
                for (int rt=0; rt<4; rt++){
#pragma unroll
                    for (int r4=0; r4<4; r4++){
                        float rg = fast_sig(acc[rt][r4] + brr[jh]);
                        float zg = fast_sig(acc[4+rt][r4] + bzz[jh]);
                        float ng = fast_tanh(acc[12+rt][r4] + bxn[jh] + rg*(acc[8+rt][r4] + bhn[jh]));
                        float hold = (s == 0) ? 0.f : bf2f(holdv[jh][rt][r4]);
                        holdv[jh][rt][r4] = f2bf((1.f - zg)*ng + zg*hold);
                    }
                }
            }
            __syncthreads();   // all A_l/Xcur reads (both passes) done
#pragma unroll
            for (int jh=0; jh<2; jh++)
#pragma unroll
                for (int rt=0; rt<4; rt++)
#pragma unroll
                    for (int r4=0; r4<4; r4++){
                        int ha = ((((rt<<2)+w)*64 + (((jh<<1)+(m>>3))<<4) + (quad<<2)+r4)<<3) + (m&7);
                        A_l[ha] = holdv[jh][rt][r4];
                    }
            __syncthreads();   // A_l ready for next step / out-GEMM
        }
        // output GEMM: wave w -> cols (w<<5)..(w<<5)+31, K=128
        float4v zero = {0.f,0.f,0.f,0.f};
        float4v acco[8];   // [cto2][rt4]
#pragma unroll
        for (int i=0;i<8;i++) acco[i] = zero;
#pragma unroll 1
        for (int c=0;c<4;c++){
            short8v afr[4];
#pragma unroll
            for (int rt=0;rt<4;rt++)
                afr[rt] = *(const short8v*)(A_l + (((rt<<2) + c)*64 + lane)*8);
#pragma unroll
            for (int cto=0;cto<2;cto++){
                short8v bf = *(const short8v*)(WoF + (((size_t)(c*8 + (w<<1)+cto))*64 + lane)*8);
#pragma unroll
                for (int rt=0;rt<4;rt++)
                    acco[(cto<<2)+rt] = __builtin_amdgcn_mfma_f32_16x16x32_bf16(afr[rt], bf, acco[(cto<<2)+rt], 0,0,0);
            }
        }
#pragma unroll
        for (int cto=0; cto<2; cto++){
            int col = (w<<5) + (cto<<4) + m;
            float bb = bo[col];
#pragma unroll
            for (int rt=0; rt<4; rt++){
#pragma unroll
                for (int r4=0; r4<4; r4++){
                    int row = row0 + (rt<<4) + (quad<<2) + r4;
                    if (row < NND) out[(size_t)row*128 + col] = acco[(cto<<2)+rt][r4] + bb;
                }
            }
        }
    }
}

extern "C" void kernel_launch(void* const* d_in, const int* in_sizes, int n_in,
                              void* d_out, int out_size, void* d_ws, size_t ws_size,
                              hipStream_t stream)
{
    const float* node_attr = (const float*)d_in[0];
    const int*   edge_index= (const int*)  d_in[1];
    const float* noise = (const float*)d_in[3];
    const float* W1 = (const float*)d_in[4];
    const float* b1 = (const float*)d_in[5];
    const float* W2 = (const float*)d_in[6];
    const float* b2 = (const float*)d_in[7];
    const float* Wx = (const float*)d_in[8];
    const float* Wh = (const float*)d_in[9];
    const float* bx = (const float*)d_in[10];
    const float* bh = (const float*)d_in[11];
    const float* Wo = (const float*)d_in[12];
    const float* bo = (const float*)d_in[13];
    const int* dst = edge_index + (size_t)NND*DEG;
    float* out = (float*)d_out;
    if (ws_size < WS_NEED) return;

    char* ws = (char*)d_ws;
    float* hpre = (float*)(ws + OFF_HPRE);
    float* proj = (float*)(ws + OFF_PROJ);
    unsigned short* Xb  = (unsigned short*)(ws + OFF_XB);
    int* idxb = (int*)(ws + OFF_IDX);
    unsigned short* BqF = (unsigned short*)(ws + OFF_BQF);
    unsigned short* WoF = (unsigned short*)(ws + OFF_WOF);

    // fused setup: pack X/BqF/WoF + iota, one launch
    k_setup<<<dim3(6250), dim3(256), 0, stream>>>(node_attr, Wx, Wh, Wo, Xb, BqF, WoF, idxb);

    // walk phase (fp32)
    k_projall<<<dim3(196, 3), dim3(256), 0, stream>>>(node_attr, W1, b1, hpre, proj);
    k_walk4<<<dim3(3125), dim3(256), 0, stream>>>(hpre, proj, dst, W2, b2, noise, idxb);

    // GRU (all 5 steps) + output GEMM: 3 blocks/CU register-diet version
    k_gru5<<<dim3(768), dim3(256), 0, stream>>>(Xb, BqF, WoF, bx, bh, bo, idxb, out);
}

// Round 10
// 342.363 us; speedup vs baseline: 1.2430x; 1.2430x over previous
//
#include <hip/hip_runtime.h>
#include <math.h>

#define NND 50000
#define DEG 16

typedef __attribute__((ext_vector_type(8))) short short8v;
typedef __attribute__((ext_vector_type(4))) float float4v;

// ---- workspace layout (bytes) ----
#define OFF_HPRE 0ULL            // N x 64 f32
#define OFF_PROJ 12800000ULL     // 4 x N x 64 f32
#define OFF_XB   64000000ULL     // N x 128 bf16
#define OFF_IDX  102400000ULL    // 5*N int
#define OFF_BQF  103600384ULL    // 4y x 8c x 8ct x 64 x 8 bf16 = 256 KB
#define OFF_WOF  103862528ULL    // 4c x 8ct x 64 x 8 bf16 = 32 KB
#define WS_NEED  103895296ULL

#define LOG2E 1.44269504088896f

__device__ __forceinline__ float fast_sig(float x){
    return __builtin_amdgcn_rcpf(1.f + __builtin_amdgcn_exp2f(-LOG2E*x));
}
__device__ __forceinline__ float fast_tanh(float x){
    return fmaf(-2.f, __builtin_amdgcn_rcpf(1.f + __builtin_amdgcn_exp2f((2.f*LOG2E)*x)), 1.f);
}
__device__ __forceinline__ unsigned short f2bf(float f){
    unsigned int u = __float_as_uint(f);
    u += 0x7FFFu + ((u >> 16) & 1u);
    return (unsigned short)(u >> 16);
}
__device__ __forceinline__ float bf2f(unsigned short h){
    return __uint_as_float(((unsigned int)h) << 16);
}

// ---------------- fused projall + setup ----------------
// projall (blocks 0..587) and setup (blocks 588..6837) are mutually
// independent (setup writes Xb/BqF/WoF/idxb; projall writes hpre/proj; both
// only read inputs). projall blocks dispatch FIRST and fill all 2-block/CU
// slots; setup blocks backfill as projall blocks retire -> setup's ~15-20us
// of BW-bound work hides in projall's stall shadow. Both paths byte-identical
// to the standalone r8 kernels -> bit-exact.
__global__ __launch_bounds__(256,2) void k_proj_setup(const float* __restrict__ A,
    const float* __restrict__ W1, const float* __restrict__ bias1,
    const float* __restrict__ Wx, const float* __restrict__ Wh,
    const float* __restrict__ Wo,
    float* __restrict__ hpre, float* __restrict__ proj,
    unsigned short* __restrict__ Xb, unsigned short* __restrict__ BqF,
    unsigned short* __restrict__ WoF, int* __restrict__ idx0)
{
    __shared__ float Alt[32][320];     // [k][sr], sr = row + (row>>4)*4 (40KB)
    __shared__ float Bl[32][140];      // [k][scol], scol = col + (col>>5)*4 (17.5KB)
    const int tid = threadIdx.x;

    if (blockIdx.x >= 588){
        // ---- setup role ----
        const int b = blockIdx.x - 588;
        {
            int i = b*256 + tid;
            if (i < NND*32){
                float4 v = *(const float4*)(A + (size_t)i*4);
                unsigned long long pk = (unsigned long long)f2bf(v.x)
                    | ((unsigned long long)f2bf(v.y) << 16)
                    | ((unsigned long long)f2bf(v.z) << 32)
                    | ((unsigned long long)f2bf(v.w) << 48);
                *(unsigned long long*)(Xb + (size_t)i*4) = pk;
            }
        }
        if (b < 512){
            int i = b*256 + tid;  // 131072
            int jj = i & 7, lane = (i>>3)&63, ct = (i>>9)&7, c = (i>>12)&7, y = i>>15;
            int g = ct>>1, jh = ct&1, mm = lane&15, quad = lane>>4;
            int jg = (y<<5) + (jh<<4) + mm;
            int k = (c<<5) + (quad<<3) + jj;
            float v = 0.f;
            if (k < 128){
                if (g < 3) v = Wh[k*384 + g*128 + jg];
            } else {
                int kk = k - 128;
                if (g == 0)      v = Wx[kk*384 + jg];
                else if (g == 1) v = Wx[kk*384 + 128 + jg];
                else if (g == 3) v = Wx[kk*384 + 256 + jg];
            }
            BqF[i] = f2bf(v);
        } else if (b < 576){
            int i = (b-512)*256 + tid;  // 16384
            int jj = i & 7, lane = (i>>3)&63, ct = (i>>9)&7, c = i>>12;
            int n = (ct<<4) + (lane&15);
            int k = (c<<5) + ((lane>>4)<<3) + jj;
            WoF[i] = f2bf(Wo[k*128 + n]);
        } else if (b < 772){
            int i = (b-576)*256 + tid;
            if (i < NND) idx0[i] = i;
        }
        return;
    }

    // ---- projall role (r8 v8, verbatim): blocks 0..587, rb-major then z ----
    const int rb = blockIdx.x % 196;
    const int z  = blockIdx.x / 196;   // 0:{y0,y1} 1:{y2,y3} 2:{y4}
    const int row0 = rb << 8;          // 256 rows/block
    const int row_t = tid >> 4, col_t = tid & 15;
    const int sr_st = tid + ((tid>>4)<<2);   // staging swizzled row
    int gr_st = row0 + tid; if (gr_st >= NND) gr_st = NND-1;
    const float* ap = A + (size_t)gr_st*128;

    if (z < 2){
        float4 acc[16][2];
#pragma unroll
        for (int j=0;j<16;j++){ acc[j][0]=make_float4(0,0,0,0); acc[j][1]=make_float4(0,0,0,0); }
        const int cb = col_t << 3;
        const int scb = cb + ((cb>>5)<<2);
        for (int k0 = 0; k0 < 128; k0 += 32){
#pragma unroll
            for (int u=0;u<8;u++){
                float4 v = *(const float4*)(ap + k0 + (u<<2));
                Alt[(u<<2)+0][sr_st] = v.x; Alt[(u<<2)+1][sr_st] = v.y;
                Alt[(u<<2)+2][sr_st] = v.z; Alt[(u<<2)+3][sr_st] = v.w;
            }
#pragma unroll
            for (int i=0;i<4;i++){
                int p = (i<<8) + tid;
                int ch = p >> 9, rem = p & 511;
                int bk = rem >> 4, bc = (rem & 15) << 2;
                int col = (ch<<6) + bc;
                int sc = col + ((col>>5)<<2);
                *(float4*)(&Bl[bk][sc]) =
                    *(const float4*)(W1 + (size_t)(((z*2+ch)<<7) + k0 + bk)*64 + bc);
            }
            __syncthreads();
#pragma unroll 2
            for (int k=0;k<32;k++){
                const float* ar = &Alt[k][row_t*20];
                float4 a0 = *(const float4*)(ar);
                float4 a1 = *(const float4*)(ar+4);
                float4 a2 = *(const float4*)(ar+8);
                float4 a3 = *(const float4*)(ar+12);
                float4 b0 = *(const float4*)(&Bl[k][scb]);
                float4 b1 = *(const float4*)(&Bl[k][scb+4]);
                float av[16] = {a0.x,a0.y,a0.z,a0.w, a1.x,a1.y,a1.z,a1.w,
                                a2.x,a2.y,a2.z,a2.w, a3.x,a3.y,a3.z,a3.w};
#pragma unroll
                for (int j=0;j<16;j++){
                    acc[j][0].x = fmaf(av[j], b0.x, acc[j][0].x);
                    acc[j][0].y = fmaf(av[j], b0.y, acc[j][0].y);
                    acc[j][0].z = fmaf(av[j], b0.z, acc[j][0].z);
                    acc[j][0].w = fmaf(av[j], b0.w, acc[j][0].w);
                    acc[j][1].x = fmaf(av[j], b1.x, acc[j][1].x);
                    acc[j][1].y = fmaf(av[j], b1.y, acc[j][1].y);
                    acc[j][1].z = fmaf(av[j], b1.z, acc[j][1].z);
                    acc[j][1].w = fmaf(av[j], b1.w, acc[j][1].w);
                }
            }
            __syncthreads();
        }
        float* dlo = (z==0) ? hpre : (proj + (size_t)(2*z-1)*NND*64);
        float* dhi = proj + (size_t)(2*z)*NND*64;
        float* dstp = (col_t < 8) ? dlo : dhi;
        const int ccol = (col_t & 7) << 3;
        float4 bb0 = make_float4(0,0,0,0), bb1 = make_float4(0,0,0,0);
        if (z == 0 && col_t < 8){
            bb0 = *(const float4*)(bias1 + ccol);
            bb1 = *(const float4*)(bias1 + ccol + 4);
        }
#pragma unroll
        for (int j=0;j<16;j++){
            int gr = row0 + (row_t<<4) + j;
            if (gr < NND){
                float4 o0 = make_float4(acc[j][0].x+bb0.x, acc[j][0].y+bb0.y,
                                        acc[j][0].z+bb0.z, acc[j][0].w+bb0.w);
                float4 o1 = make_float4(acc[j][1].x+bb1.x, acc[j][1].y+bb1.y,
                                        acc[j][1].z+bb1.z, acc[j][1].w+bb1.w);
                *(float4*)(dstp + ((size_t)gr<<6) + ccol)     = o0;
                *(float4*)(dstp + ((size_t)gr<<6) + ccol + 4) = o1;
            }
        }
    } else {
        float4 acc[16];
#pragma unroll
        for (int j=0;j<16;j++) acc[j] = make_float4(0,0,0,0);
        const int cb = col_t << 2;
        const int scb = cb + ((cb>>5)<<2);
        for (int k0 = 0; k0 < 128; k0 += 32){
#pragma unroll
            for (int u=0;u<8;u++){
                float4 v = *(const float4*)(ap + k0 + (u<<2));
                Alt[(u<<2)+0][sr_st] = v.x; Alt[(u<<2)+1][sr_st] = v.y;
                Alt[(u<<2)+2][sr_st] = v.z; Alt[(u<<2)+3][sr_st] = v.w;
            }
#pragma unroll
            for (int i=0;i<2;i++){
                int p = (i<<8) + tid;     // 512 float4
                int bk = p >> 4, bc = (p & 15) << 2;
                int sc = bc + ((bc>>5)<<2);
                *(float4*)(&Bl[bk][sc]) =
                    *(const float4*)(W1 + (size_t)((4<<7) + k0 + bk)*64 + bc);
            }
            __syncthreads();
#pragma unroll 2
            for (int k=0;k<32;k++){
                const float* ar = &Alt[k][row_t*20];
                float4 a0 = *(const float4*)(ar);
                float4 a1 = *(const float4*)(ar+4);
                float4 a2 = *(const float4*)(ar+8);
                float4 a3 = *(const float4*)(ar+12);
                float4 b0 = *(const float4*)(&Bl[k][scb]);
                float av[16] = {a0.x,a0.y,a0.z,a0.w, a1.x,a1.y,a1.z,a1.w,
                                a2.x,a2.y,a2.z,a2.w, a3.x,a3.y,a3.z,a3.w};
#pragma unroll
                for (int j=0;j<16;j++){
                    acc[j].x = fmaf(av[j], b0.x, acc[j].x);
                    acc[j].y = fmaf(av[j], b0.y, acc[j].y);
                    acc[j].z = fmaf(av[j], b0.z, acc[j].z);
                    acc[j].w = fmaf(av[j], b0.w, acc[j].w);
                }
            }
            __syncthreads();
        }
        float* dstp = proj + (size_t)3*NND*64;
#pragma unroll
        for (int j=0;j<16;j++){
            int gr = row0 + (row_t<<4) + j;
            if (gr < NND)
                *(float4*)(dstp + ((size_t)gr<<6) + cb) = acc[j];
        }
    }
}

// ---------------- walk4 v3 (round-8, kept): reduce-scatter logits ----------------
// HBM/L2-miss-path bound: dur == FETCH/3.5TB/s; 332MB is structural
// (proj[t]=12.8MB > 4MB XCD L2, random gathers re-pulled per XCD per step).
__global__ __launch_bounds__(256) void k_walk4(
    const float* __restrict__ hpre0, const float* __restrict__ proj,
    const int* __restrict__ dst, const float* __restrict__ W2,
    const float* __restrict__ b2, const float* __restrict__ noise,
    int* __restrict__ idxb)
{
    const int tid = threadIdx.x;
    const int sg = tid >> 4, l = tid & 15;
    const int gi = (blockIdx.x << 4) + sg;
    float4 hp = *(const float4*)(hpre0 + ((size_t)gi<<6) + (l<<2));
    float4 w2 = *(const float4*)(W2 + (l<<2));
    const float b2s = b2[0];
    int curv = gi;
#pragma unroll 1
    for (int t=0; t<4; t++){
        const float* pj = proj + (size_t)t*NND*64;
        const int base = curv*DEG;
        const int nbr = dst[base + l];              // per-lane id (for sel shfl)
        int4 nb0 = *(const int4*)(dst + base);      // uniform in subgroup: L1 broadcast
        int4 nb1 = *(const int4*)(dst + base + 4);
        int4 nb2 = *(const int4*)(dst + base + 8);
        int4 nb3 = *(const int4*)(dst + base + 12);
        int nds[16] = {nb0.x,nb0.y,nb0.z,nb0.w, nb1.x,nb1.y,nb1.z,nb1.w,
                       nb2.x,nb2.y,nb2.z,nb2.w, nb3.x,nb3.y,nb3.z,nb3.w};
        float4 val[16];
#pragma unroll
        for (int d=0; d<16; d++)
            val[d] = *(const float4*)(pj + ((size_t)nds[d]<<6) + (l<<2));
        float q[16];
#pragma unroll
        for (int d=0; d<16; d++){
            float4 v = val[d];
            float qq =  fmaxf(hp.x+v.x,0.f)*w2.x;
            qq = fmaf(fmaxf(hp.y+v.y,0.f), w2.y, qq);
            qq = fmaf(fmaxf(hp.z+v.z,0.f), w2.z, qq);
            qq = fmaf(fmaxf(hp.w+v.w,0.f), w2.w, qq);
            q[d] = qq;
        }
        // reduce-scatter butterfly: 15 shuffles, logit l ends in lane l. BIT-EXACT.
        float r1[8];
#pragma unroll
        for (int i=0;i<8;i++){
            float a = q[2*i], b = q[2*i+1];
            float send = (l&1) ? a : b;
            float keep = (l&1) ? b : a;
            r1[i] = keep + __shfl_xor(send, 1, 16);
        }
        float r2[4];
#pragma unroll
        for (int i=0;i<4;i++){
            float a = r1[2*i], b = r1[2*i+1];
            float send = (l&2) ? a : b;
            float keep = (l&2) ? b : a;
            r2[i] = keep + __shfl_xor(send, 2, 16);
        }
        float r3[2];
#pragma unroll
        for (int i=0;i<2;i++){
            float a = r2[2*i], b = r2[2*i+1];
            float send = (l&4) ? a : b;
            float keep = (l&4) ? b : a;
            r3[i] = keep + __shfl_xor(send, 4, 16);
        }
        float lp;
        {
            float a = r3[0], b = r3[1];
            float send = (l&8) ? a : b;
            float keep = (l&8) ? b : a;
            lp = keep + __shfl_xor(send, 8, 16) + b2s;
        }
        float mx = lp;
#pragma unroll
        for (int off=8; off; off>>=1) mx = fmaxf(mx, __shfl_xor(mx, off, 16));
        float s = expf(lp - mx);
#pragma unroll
        for (int off=8; off; off>>=1) s += __shfl_xor(s, off, 16);
        float p = expf(lp - mx - logf(s)) + noise[(size_t)t*NND*DEG + ((size_t)gi<<4) + l];
        float bv = p; int bi = l;
#pragma unroll
        for (int off=8; off; off>>=1){
            float ov = __shfl_xor(bv, off, 16);
            int   oi = __shfl_xor(bi, off, 16);
            if (ov > bv || (ov == bv && oi < bi)){ bv = ov; bi = oi; }
        }
        int sel = __shfl(nbr, bi, 16);
        if (l == 0) idxb[(size_t)(t+1)*NND + gi] = sel;
        float4 u = *(const float4*)(pj + ((size_t)sel<<6) + (l<<2));
        hp.x += u.x; hp.y += u.y; hp.z += u.z; hp.w += u.w;
        curv = sel;
    }
}

// ---------------- fully fused GRU (5 steps) + output GEMM ----------------
// r8 version (known-good ~95us), REVERTED from r9's two-pass diet (which
// doubled LDS reads + serial MFMA chain: 173us, MfmaUtil 10.7%).
// 116 VGPR + 128 AGPR (acc[32]) = 244 -> 2 waves/SIMD structural cap.
// A_l double-buffered -> 1 barrier/step; early x-staging overlaps MFMA;
// 512-block grid-stride; zero-frag skip (bit-exact); c loops forced rolled.
__global__ __launch_bounds__(256,2) void k_gru5(
    const unsigned short* __restrict__ Xb,
    const unsigned short* __restrict__ BqF,
    const unsigned short* __restrict__ WoF,
    const float* __restrict__ bx, const float* __restrict__ bh,
    const float* __restrict__ bo, const int* __restrict__ idxb,
    float* __restrict__ out)
{
    __shared__ unsigned short A_l[2][8192];  // h frags, double-buffered (32KB)
    __shared__ unsigned short X_l[16384];    // x frags, 2 buffers of 8192 (32KB)
    const int tid = threadIdx.x;
    const int w = tid >> 6, lane = tid & 63;
    const int m = lane & 15, quad = lane >> 4;
    const int r = tid & 63, q = tid >> 6;
    const int rt_s = r >> 4, m_s = r & 15;
    float brr[2], bzz[2], bxn[2], bhn[2];
#pragma unroll
    for (int jh=0; jh<2; jh++){
        int j = (w<<5) + (jh<<4) + m;
        brr[jh] = bx[j] + bh[j];
        bzz[jh] = bx[128+j] + bh[128+j];
        bxn[jh] = bx[256+j];
        bhn[jh] = bh[256+j];
    }

#pragma unroll 1
    for (int tb = blockIdx.x; tb < 782; tb += 512){
        const int row0 = tb << 6;
        int gr = row0 + r; if (gr >= NND) gr = NND-1;
        unsigned short holdv[2][4][4];
        short8v xv[4];
        {
            const int xr = idxb[gr];
            const unsigned short* xrow = Xb + (size_t)xr*128 + (q<<5);
#pragma unroll
            for (int u=0;u<4;u++) xv[u] = *(const short8v*)(xrow + (u<<3));
#pragma unroll
            for (int u=0;u<4;u++)
                *(short8v*)(X_l + (((rt_s<<2)+q)*64 + (u<<4) + m_s)*8) = xv[u];
            const int xr1 = idxb[NND + gr];
            const unsigned short* xrow1 = Xb + (size_t)xr1*128 + (q<<5);
#pragma unroll
            for (int u=0;u<4;u++) xv[u] = *(const short8v*)(xrow1 + (u<<3));
        }
        __syncthreads();   // X_l[0] ready (also guards prev tile's A_l reads)

#pragma unroll 1
        for (int s=0; s<5; s++){
            const unsigned short* Acur = A_l[s&1];
            const unsigned short* Xcur = X_l + ((s&1)<<13);
            // EARLY x-staging: Xnxt parity was last read in step s-1 (barrier
            // passed) -> safe to write now; overlaps the MFMA section below.
            if (s < 4){
                unsigned short* Xnxt = X_l + (((s+1)&1)<<13);
#pragma unroll
                for (int u=0;u<4;u++)
                    *(short8v*)(Xnxt + (((rt_s<<2)+q)*64 + (u<<4) + m_s)*8) = xv[u];
                if (s < 3){
                    const int xr = idxb[(size_t)(s+2)*NND + gr];
                    const unsigned short* xrow = Xb + (size_t)xr*128 + (q<<5);
#pragma unroll
                    for (int u=0;u<4;u++) xv[u] = *(const short8v*)(xrow + (u<<3));
                }
            }
            float4v zero = {0.f,0.f,0.f,0.f};
            float4v acc[32];   // [ct8][rt4]
#pragma unroll
            for (int i=0;i<32;i++) acc[i] = zero;
            if (s > 0){
#pragma unroll 1
                for (int c=0;c<4;c++){
                    short8v afr[4];
#pragma unroll
                    for (int rt=0;rt<4;rt++)
                        afr[rt] = *(const short8v*)(Acur + (((rt<<2) + c)*64 + lane)*8);
                    const unsigned short* bp = BqF + ((((size_t)w*8 + c)*8)*64 + lane)*8;
#pragma unroll
                    for (int ct=0;ct<6;ct++){
                        short8v bf = *(const short8v*)(bp + (ct<<9));
#pragma unroll
                        for (int rt=0;rt<4;rt++)
                            acc[(ct<<2)+rt] = __builtin_amdgcn_mfma_f32_16x16x32_bf16(afr[rt], bf, acc[(ct<<2)+rt], 0,0,0);
                    }
                }
            }
#pragma unroll 1
            for (int c=4;c<8;c++){
                short8v afr[4];
#pragma unroll
                for (int rt=0;rt<4;rt++)
                    afr[rt] = *(const short8v*)(Xcur + (((rt<<2) + (c&3))*64 + lane)*8);
                const unsigned short* bp = BqF + ((((size_t)w*8 + c)*8)*64 + lane)*8;
#pragma unroll
                for (int cti=0;cti<6;cti++){
                    const int ct = (cti < 4) ? cti : (cti + 2);
                    short8v bf = *(const short8v*)(bp + (ct<<9));
#pragma unroll
                    for (int rt=0;rt<4;rt++)
                        acc[(ct<<2)+rt] = __builtin_amdgcn_mfma_f32_16x16x32_bf16(afr[rt], bf, acc[(ct<<2)+rt], 0,0,0);
                }
            }
#pragma unroll
            for (int jh=0; jh<2; jh++){
#pragma unroll
                for (int rt=0; rt<4; rt++){
#pragma unroll
                    for (int r4=0; r4<4; r4++){
                        float rg = fast_sig(acc[(jh<<2)+rt][r4] + brr[jh]);
                        float zg = fast_sig(acc[((2+jh)<<2)+rt][r4] + bzz[jh]);
                        float ng = fast_tanh(acc[((6+jh)<<2)+rt][r4] + bxn[jh] + rg*(acc[((4+jh)<<2)+rt][r4] + bhn[jh]));
                        float hold = (s == 0) ? 0.f : bf2f(holdv[jh][rt][r4]);
                        holdv[jh][rt][r4] = f2bf((1.f - zg)*ng + zg*hold);
                    }
                }
            }
            unsigned short* Anxt = A_l[(s+1)&1];
#pragma unroll
            for (int jh=0; jh<2; jh++)
#pragma unroll
                for (int rt=0; rt<4; rt++)
#pragma unroll
                    for (int r4=0; r4<4; r4++){
                        int ha = ((((rt<<2)+w)*64 + (((jh<<1)+(m>>3))<<4) + (quad<<2)+r4)<<3) + (m&7);
                        Anxt[ha] = holdv[jh][rt][r4];
                    }
            __syncthreads();   // single barrier: next-step buffers ready
        }
        const unsigned short* Afin = A_l[1];
        float4v zero = {0.f,0.f,0.f,0.f};
        float4v acco[8];   // [cto2][rt4]
#pragma unroll
        for (int i=0;i<8;i++) acco[i] = zero;
#pragma unroll 1
        for (int c=0;c<4;c++){
            short8v afr[4];
#pragma unroll
            for (int rt=0;rt<4;rt++)
                afr[rt] = *(const short8v*)(Afin + (((rt<<2) + c)*64 + lane)*8);
#pragma unroll
            for (int cto=0;cto<2;cto++){
                short8v bf = *(const short8v*)(WoF + (((size_t)(c*8 + (w<<1)+cto))*64 + lane)*8);
#pragma unroll
                for (int rt=0;rt<4;rt++)
                    acco[(cto<<2)+rt] = __builtin_amdgcn_mfma_f32_16x16x32_bf16(afr[rt], bf, acco[(cto<<2)+rt], 0,0,0);
            }
        }
#pragma unroll
        for (int cto=0; cto<2; cto++){
            int col = (w<<5) + (cto<<4) + m;
            float bb = bo[col];
#pragma unroll
            for (int rt=0; rt<4; rt++){
#pragma unroll
                for (int r4=0; r4<4; r4++){
                    int row = row0 + (rt<<4) + (quad<<2) + r4;
                    if (row < NND) out[(size_t)row*128 + col] = acco[(cto<<2)+rt][r4] + bb;
                }
            }
        }
    }
}

extern "C" void kernel_launch(void* const* d_in, const int* in_sizes, int n_in,
                              void* d_out, int out_size, void* d_ws, size_t ws_size,
                              hipStream_t stream)
{
    const float* node_attr = (const float*)d_in[0];
    const int*   edge_index= (const int*)  d_in[1];
    const float* noise = (const float*)d_in[3];
    const float* W1 = (const float*)d_in[4];
    const float* b1 = (const float*)d_in[5];
    const float* W2 = (const float*)d_in[6];
    const float* b2 = (const float*)d_in[7];
    const float* Wx = (const float*)d_in[8];
    const float* Wh = (const float*)d_in[9];
    const float* bx = (const float*)d_in[10];
    const float* bh = (const float*)d_in[11];
    const float* Wo = (const float*)d_in[12];
    const float* bo = (const float*)d_in[13];
    const int* dst = edge_index + (size_t)NND*DEG;
    float* out = (float*)d_out;
    if (ws_size < WS_NEED) return;

    char* ws = (char*)d_ws;
    float* hpre = (float*)(ws + OFF_HPRE);
    float* proj = (float*)(ws + OFF_PROJ);
    unsigned short* Xb  = (unsigned short*)(ws + OFF_XB);
    int* idxb = (int*)(ws + OFF_IDX);
    unsigned short* BqF = (unsigned short*)(ws + OFF_BQF);
    unsigned short* WoF = (unsigned short*)(ws + OFF_WOF);

    // fused projall + setup: projall blocks (0..587) dispatch first, setup
    // blocks (588..6837) backfill the stall/tail shadow.
    k_proj_setup<<<dim3(6838), dim3(256), 0, stream>>>(node_attr, W1, b1,
        Wx, Wh, Wo, hpre, proj, Xb, BqF, WoF, idxb);

    k_walk4<<<dim3(3125), dim3(256), 0, stream>>>(hpre, proj, dst, W2, b2, noise, idxb);

    // GRU (all 5 steps) + output GEMM: r8 known-good version
    k_gru5<<<dim3(512), dim3(256), 0, stream>>>(Xb, BqF, WoF, bx, bh, bo, idxb, out);
}